// Round 1
// baseline (735.874 us; speedup 1.0000x reference)
//
#include <hip/hip_runtime.h>
#include <hip/hip_bf16.h>
#include <stdint.h>

// Problem constants (fixed by setup_inputs)
#define B_  32
#define T_  4096
#define D_  768
#define A_  128
#define BT_ (B_ * T_)          // 131072 tokens
#define LN_EPS 1e-5f

typedef __attribute__((ext_vector_type(8))) short  short8;   // 8 x bf16 (4 VGPRs)
typedef __attribute__((ext_vector_type(4))) float  floatx4;  // MFMA acc

// ---------------- helpers ----------------
__device__ __forceinline__ uint32_t pack_bf16x2(float a, float b) {
    __hip_bfloat162 h = __float22bfloat162_rn(make_float2(a, b));
    union { __hip_bfloat162 h; uint32_t u; } cv; cv.h = h;
    return cv.u;   // low 16 bits = a, high = b
}

__device__ __forceinline__ uint16_t f2bf_rne(float f) {
    union { float f; uint32_t u; } cv; cv.f = f;
    uint32_t u = cv.u;
    return (uint16_t)((u + 0x7FFFu + ((u >> 16) & 1u)) >> 16);
}

// fast tanh via exp:  tanh(x) = (e^{2x}-1)/(e^{2x}+1)
__device__ __forceinline__ float fast_tanh(float x) {
    float e = __expf(2.f * x);
    return __fdividef(e - 1.f, e + 1.f);
}

// ---------------- kernel 1: Wp -> Wp^T bf16 ----------------
// Wp: (3, 768, 128) fp32  ->  wpt: (3, 128, 768) bf16
__global__ __launch_bounds__(256)
void k_wp(const float* __restrict__ Wp, uint16_t* __restrict__ wpt) {
    int o = blockIdx.x * 256 + threadIdx.x;          // 0 .. 294911
    int s   = o / (A_ * D_);
    int rem = o - s * (A_ * D_);
    int a   = rem / D_;
    int d   = rem - a * D_;
    float f = Wp[(size_t)s * (D_ * A_) + d * A_ + a];
    wpt[o] = f2bf_rne(f);
}

// ---------------- kernel 2: projection + tanh + score ----------------
// Per block: one scale s, one 128-token tile. 128(M) x 128(N=A) x 768(K) GEMM,
// 16x16x32 bf16 MFMA, 4 waves in 2x2, BK=64. Epilogue: scr = sum_a v[a]*tanh(proj+bp[a]).
__global__ __launch_bounds__(256, 2)
void k_proj_scr(const float* __restrict__ x, const uint16_t* __restrict__ wpt,
                const float* __restrict__ bp, const float* __restrict__ v,
                float* __restrict__ scr) {
    const int s    = blockIdx.x;          // fast dim: 3 scale-blocks of one tile adjacent -> LLC reuse of x
    const int tile = blockIdx.y;          // 0..1023
    const int bt0  = tile * 128;
    const int tid  = threadIdx.x;
    const int lane = tid & 63;
    const int wave = tid >> 6;
    const int wrow = (wave >> 1) * 64;    // wave row offset in tile
    const int wcol = (wave & 1) * 64;     // wave col offset
    const int l15  = lane & 15;
    const int quad = lane >> 4;

    __shared__ uint16_t xl[128][72];      // x tile, bf16, +8 pad (<=2-way bank alias = free)
    __shared__ float    scr_part[2][128];

    floatx4 acc[4][4];
#pragma unroll
    for (int i = 0; i < 4; ++i)
#pragma unroll
        for (int j = 0; j < 4; ++j) acc[i][j] = (floatx4){0.f, 0.f, 0.f, 0.f};

    const uint16_t* wps = wpt + (size_t)s * (A_ * D_);

    for (int k0 = 0; k0 < D_; k0 += 64) {
        // ---- stage x[128 x 64] fp32 -> bf16 LDS ----
#pragma unroll
        for (int q = 0; q < 4; ++q) {
            int idx = tid + 256 * q;            // 0..1023 ; 8 threads per row
            int row = idx >> 3;
            int c8  = (idx & 7) << 3;           // 0,8,...,56
            const float* gp = x + (size_t)(bt0 + row) * D_ + k0 + c8;
            float4 f0 = *(const float4*)gp;
            float4 f1 = *(const float4*)(gp + 4);
            uint4 pk;
            pk.x = pack_bf16x2(f0.x, f0.y);
            pk.y = pack_bf16x2(f0.z, f0.w);
            pk.z = pack_bf16x2(f1.x, f1.y);
            pk.w = pack_bf16x2(f1.z, f1.w);
            *(uint4*)&xl[row][c8] = pk;         // ds_write_b128
        }
        __syncthreads();

        // ---- B fragments straight from global (L1/L2-hot Wp^T) ----
        short8 bfrag[2][4];
#pragma unroll
        for (int kk = 0; kk < 2; ++kk)
#pragma unroll
            for (int j = 0; j < 4; ++j) {
                int n = wcol + j * 16 + l15;
                bfrag[kk][j] = *(const short8*)(wps + (size_t)n * D_ + k0 + kk * 32 + quad * 8);
            }

#pragma unroll
        for (int kk = 0; kk < 2; ++kk) {
            short8 afrag[4];
#pragma unroll
            for (int i = 0; i < 4; ++i)
                afrag[i] = *(const short8*)&xl[wrow + i * 16 + l15][kk * 32 + quad * 8];
#pragma unroll
            for (int i = 0; i < 4; ++i)
#pragma unroll
                for (int j = 0; j < 4; ++j)
                    acc[i][j] = __builtin_amdgcn_mfma_f32_16x16x32_bf16(
                        afrag[i], bfrag[kk][j], acc[i][j], 0, 0, 0);
        }
        __syncthreads();
    }

    // ---- epilogue: scr_row = sum_col v[col] * tanh(acc + bp[col]) ----
    float vj[4], bpj[4];
#pragma unroll
    for (int j = 0; j < 4; ++j) {
        int col = wcol + j * 16 + l15;
        vj[j]  = v[s * A_ + col];
        bpj[j] = bp[s * A_ + col];
    }
#pragma unroll
    for (int i = 0; i < 4; ++i) {
        float rs[4] = {0.f, 0.f, 0.f, 0.f};
#pragma unroll
        for (int j = 0; j < 4; ++j)
#pragma unroll
            for (int r = 0; r < 4; ++r)
                rs[r] += vj[j] * fast_tanh(acc[i][j][r] + bpj[j]);
#pragma unroll
        for (int r = 0; r < 4; ++r) {
            float t = rs[r];
            t += __shfl_xor(t, 1);
            t += __shfl_xor(t, 2);
            t += __shfl_xor(t, 4);
            t += __shfl_xor(t, 8);               // sum over the 16 lanes of this quad (same row)
            if (l15 == 0)
                scr_part[wave & 1][wrow + i * 16 + quad * 4 + r] = t;
        }
    }
    __syncthreads();
    if (tid < 128)
        scr[(size_t)s * BT_ + bt0 + tid] = scr_part[0][tid] + scr_part[1][tid];
}

// ---------------- kernel 3: window softmax + attention pool ----------------
template <int P>
__device__ __forceinline__ void softmax_win(float* wrow, int base) {
    float mx = -1e30f;
#pragma unroll
    for (int i = 0; i < P; ++i) mx = fmaxf(mx, wrow[base + i]);
    float e[P]; float sum = 0.f;
#pragma unroll
    for (int i = 0; i < P; ++i) { e[i] = __expf(wrow[base + i] - mx); sum += e[i]; }
    float sc = ((float)P / (float)T_) / sum;     // softmax weight * (1/W), W = T/P
#pragma unroll
    for (int i = 0; i < P; ++i) wrow[base + i] = e[i] * sc;
}

__global__ __launch_bounds__(256)
void k_pool(const float* __restrict__ x, const float* __restrict__ scr,
            float* __restrict__ feats) {
    const int b   = blockIdx.x;
    const int t0  = blockIdx.y * 128;
    const int tid = threadIdx.x;
    __shared__ float w[3][128];

    for (int i = tid; i < 384; i += 256) {
        int s = i >> 7, t = i & 127;
        w[s][t] = scr[(size_t)s * BT_ + b * T_ + t0 + t];
    }
    __syncthreads();

    if (tid < 64)       softmax_win<2>(&w[0][0], tid * 2);
    else if (tid < 96)  softmax_win<4>(&w[1][0], (tid - 64) * 4);
    else if (tid < 112) softmax_win<8>(&w[2][0], (tid - 96) * 8);
    __syncthreads();

    float a00=0,a01=0,a02=0, a10=0,a11=0,a12=0, a20=0,a21=0,a22=0;
    const float* xp = x + ((size_t)b * T_ + t0) * D_;
    for (int t = 0; t < 128; ++t) {
        float x0 = xp[t * D_ + tid];
        float x1 = xp[t * D_ + tid + 256];
        float x2 = xp[t * D_ + tid + 512];
        float w0 = w[0][t], w1 = w[1][t], w2 = w[2][t];
        a00 += w0 * x0; a01 += w0 * x1; a02 += w0 * x2;
        a10 += w1 * x0; a11 += w1 * x1; a12 += w1 * x2;
        a20 += w2 * x0; a21 += w2 * x1; a22 += w2 * x2;
    }
    atomicAdd(&feats[(0 * B_ + b) * D_ + tid      ], a00);
    atomicAdd(&feats[(0 * B_ + b) * D_ + tid + 256], a01);
    atomicAdd(&feats[(0 * B_ + b) * D_ + tid + 512], a02);
    atomicAdd(&feats[(1 * B_ + b) * D_ + tid      ], a10);
    atomicAdd(&feats[(1 * B_ + b) * D_ + tid + 256], a11);
    atomicAdd(&feats[(1 * B_ + b) * D_ + tid + 512], a12);
    atomicAdd(&feats[(2 * B_ + b) * D_ + tid      ], a20);
    atomicAdd(&feats[(2 * B_ + b) * D_ + tid + 256], a21);
    atomicAdd(&feats[(2 * B_ + b) * D_ + tid + 512], a22);
}

// ---------------- kernel 4a: ms = feats_cat @ Wf (k-split, atomics) ----------------
__global__ __launch_bounds__(256)
void k_ms(const float* __restrict__ feats, const float* __restrict__ Wf,
          float* __restrict__ ms) {
    const int dchunk = blockIdx.x;   // 0..5  (128 cols each)
    const int kchunk = blockIdx.y;   // 0..31 (72 k each)
    const int k0  = kchunk * 72;
    const int tid = threadIdx.x;
    __shared__ float fl[32][72];     // feats_cat[b][k0+kk]

    for (int i = tid; i < 32 * 72; i += 256) {
        int bb = i / 72, kk = i - bb * 72;
        int k  = k0 + kk;
        int s  = k / D_;
        int d  = k - s * D_;
        fl[bb][kk] = feats[(size_t)(s * B_ + bb) * D_ + d];
    }
    __syncthreads();

    const int c     = dchunk * 128 + (tid & 127);
    const int brow0 = (tid >> 7) * 16;
    float acc[16];
#pragma unroll
    for (int r = 0; r < 16; ++r) acc[r] = 0.f;

    for (int kk = 0; kk < 72; ++kk) {
        float wv = Wf[(size_t)(k0 + kk) * D_ + c];
#pragma unroll
        for (int r = 0; r < 16; ++r) acc[r] += fl[brow0 + r][kk] * wv;
    }
#pragma unroll
    for (int r = 0; r < 16; ++r)
        atomicAdd(&ms[(size_t)(brow0 + r) * D_ + c], acc[r]);
}

// ---------------- kernel 4b: bias + LayerNorm ----------------
__global__ __launch_bounds__(256)
void k_ln(const float* __restrict__ ms, const float* __restrict__ bf,
          const float* __restrict__ gamma, const float* __restrict__ beta,
          float* __restrict__ out) {
    const int b = blockIdx.x, tid = threadIdx.x;
    float vals[3]; float sum = 0.f, sq = 0.f;
#pragma unroll
    for (int c = 0; c < 3; ++c) {
        int d = tid + c * 256;
        float vv = ms[(size_t)b * D_ + d] + bf[d];
        vals[c] = vv; sum += vv; sq += vv * vv;
    }
#pragma unroll
    for (int m = 1; m < 64; m <<= 1) { sum += __shfl_xor(sum, m); sq += __shfl_xor(sq, m); }
    __shared__ float s1[4], s2[4];
    const int wave = tid >> 6;
    if ((tid & 63) == 0) { s1[wave] = sum; s2[wave] = sq; }
    __syncthreads();
    sum = s1[0] + s1[1] + s1[2] + s1[3];
    sq  = s2[0] + s2[1] + s2[2] + s2[3];
    float mu   = sum * (1.f / (float)D_);
    float var  = sq * (1.f / (float)D_) - mu * mu;
    float rstd = rsqrtf(var + LN_EPS);
#pragma unroll
    for (int c = 0; c < 3; ++c) {
        int d = tid + c * 256;
        out[(size_t)b * D_ + d] = (vals[c] - mu) * rstd * gamma[d] + beta[d];
    }
}

// ---------------- launcher ----------------
extern "C" void kernel_launch(void* const* d_in, const int* in_sizes, int n_in,
                              void* d_out, int out_size, void* d_ws, size_t ws_size,
                              hipStream_t stream) {
    const float* x     = (const float*)d_in[0];
    const float* Wp    = (const float*)d_in[1];
    const float* bp    = (const float*)d_in[2];
    const float* v     = (const float*)d_in[3];
    const float* Wf    = (const float*)d_in[4];
    const float* bfv   = (const float*)d_in[5];
    const float* gamma = (const float*)d_in[6];
    const float* beta  = (const float*)d_in[7];
    float* out = (float*)d_out;

    // ws layout (bytes):
    //   [0, 589824)            Wp^T bf16  (3*128*768 ushort)
    //   [589824, 2162688)      scr fp32   (3*B*T)
    //   [2162688, 2457600)     feats fp32 (3*B*768)   -- atomically accumulated
    //   [2457600, 2555904)     ms fp32    (B*768)     -- atomically accumulated
    char* ws = (char*)d_ws;
    uint16_t* wpt   = (uint16_t*)ws;
    float*    scr   = (float*)(ws + 589824);
    float*    feats = (float*)(ws + 2162688);
    float*    ms    = (float*)(ws + 2457600);

    hipMemsetAsync(feats, 0, 294912 + 98304, stream);     // zero feats + ms
    k_wp      <<<1152, 256, 0, stream>>>(Wp, wpt);
    k_proj_scr<<<dim3(3, 1024), 256, 0, stream>>>(x, wpt, bp, v, scr);
    k_pool    <<<dim3(B_, T_ / 128), 256, 0, stream>>>(x, scr, feats);
    k_ms      <<<dim3(6, 32), 256, 0, stream>>>(feats, Wf, ms);
    k_ln      <<<B_, 256, 0, stream>>>(ms, bfv, gamma, beta, out);
}